// Round 8
// baseline (615.134 us; speedup 1.0000x reference)
//
#include <hip/hip_runtime.h>

#define NN 50000
#define NPAD 50048   // rows padded to multiple of 64 for MFMA tiles
#define NE 800000
#define FIN 64
#define H 128
#define NG 16
#define POOL_BLOCKS 200
#define POOL_NODES 250
#define SCAN_BLOCKS 196  // ceil(NN/256)
#define NBUCK 98         // buckets of 512 dst nodes
#define FILLA_BLOCKS 64
#define FILLA_CHUNK (NE / FILLA_BLOCKS)  // 12500
#define CHUNK_U 16       // uints per node per feature-chunk (32 feats)

typedef __bf16 bf16x8 __attribute__((ext_vector_type(8)));
typedef float f32x4 __attribute__((ext_vector_type(4)));

// ---- helpers ----
__device__ inline unsigned short bf16r(float x) {
    unsigned int u = __float_as_uint(x);
    return (unsigned short)((u + 0x7fffu + ((u >> 16) & 1u)) >> 16);
}
__device__ inline unsigned int pack_bf16x2(float a, float b) {
    return (unsigned int)bf16r(a) | ((unsigned int)bf16r(b) << 16);
}
__device__ inline float bf_lo(unsigned int u) { return __uint_as_float(u << 16); }
__device__ inline float bf_hi(unsigned int u) { return __uint_as_float(u & 0xffff0000u); }

// ================= CSR build =================
__global__ __launch_bounds__(256) void hist_kernel(const int* __restrict__ dst,
                                                   int* __restrict__ cnt) {
    int e = blockIdx.x * 256 + threadIdx.x;
    if (e < NE) atomicAdd(&cnt[dst[e]], 1);
}

__global__ __launch_bounds__(256) void scanA_kernel(const int* __restrict__ cnt,
                                                    int* __restrict__ bsum) {
    __shared__ int red[4];
    int i = blockIdx.x * 256 + threadIdx.x;
    int v = (i < NN) ? cnt[i] : 0;
    for (int off = 32; off > 0; off >>= 1) v += __shfl_down(v, off);
    if ((threadIdx.x & 63) == 0) red[threadIdx.x >> 6] = v;
    __syncthreads();
    if (threadIdx.x == 0) bsum[blockIdx.x] = red[0] + red[1] + red[2] + red[3];
}

__global__ __launch_bounds__(256) void scanB_kernel(int* __restrict__ bsum) {
    __shared__ int s[256];
    int t = threadIdx.x;
    int v = (t < SCAN_BLOCKS) ? bsum[t] : 0;
    s[t] = v;
    __syncthreads();
    for (int off = 1; off < 256; off <<= 1) {
        int u = (t >= off) ? s[t - off] : 0;
        __syncthreads();
        s[t] += u;
        __syncthreads();
    }
    if (t < SCAN_BLOCKS) bsum[t] = s[t] - v;  // exclusive
}

// scanC: rowptr/cursor + dinv + bucket bases (gbase[b] = rowptr[b*512])
__global__ __launch_bounds__(256) void scanC_kernel(const int* __restrict__ cnt,
                                                    const int* __restrict__ bsum,
                                                    int* __restrict__ rowptr,
                                                    int* __restrict__ cursor,
                                                    float* __restrict__ dinv,
                                                    int* __restrict__ gbase) {
    __shared__ int s[256];
    int t = threadIdx.x;
    int i = blockIdx.x * 256 + t;
    int v = (i < NN) ? cnt[i] : 0;
    s[t] = v;
    __syncthreads();
    for (int off = 1; off < 256; off <<= 1) {
        int u = (t >= off) ? s[t - off] : 0;
        __syncthreads();
        s[t] += u;
        __syncthreads();
    }
    if (i < NN) {
        int ex = bsum[blockIdx.x] + s[t] - v;
        rowptr[i] = ex;
        cursor[i] = ex;
        dinv[i] = rsqrtf((float)v + 1.0f);  // +1 self-loop
        if ((i & 511) == 0) gbase[i >> 9] = ex;
    }
    if (i == NN - 1) rowptr[NN] = NE;
}

// fillA: bucket edges by dst>>9 (contiguous appends -> merged writebacks)
__global__ __launch_bounds__(256) void fillA_kernel(const int* __restrict__ ei,
                                                    int* __restrict__ gbase,
                                                    unsigned int* __restrict__ ebuf) {
    __shared__ int hist[128];
    __shared__ int base[128];
    const int t = threadIdx.x;
    if (t < 128) hist[t] = 0;
    __syncthreads();
    const int e0 = blockIdx.x * FILLA_CHUNK;
    for (int e = e0 + t; e < e0 + FILLA_CHUNK; e += 256)
        atomicAdd(&hist[ei[NE + e] >> 9], 1);
    __syncthreads();
    if (t < 128) {
        int h = (t < NBUCK) ? hist[t] : 0;
        base[t] = h ? atomicAdd(&gbase[t], h) : 0;
    }
    __syncthreads();
    for (int e = e0 + t; e < e0 + FILLA_CHUNK; e += 256) {
        int d = ei[NE + e];
        int s = ei[e];
        int pos = atomicAdd(&base[d >> 9], 1);
        ebuf[pos] = (unsigned int)s | ((unsigned int)d << 16);
    }
}

// fillB: one block per bucket; scatter within the bucket's csr window
__global__ __launch_bounds__(256) void fillB_kernel(const unsigned int* __restrict__ ebuf,
                                                    const int* __restrict__ rowptr,
                                                    int* __restrict__ cursor,
                                                    int* __restrict__ csr) {
    const int b = blockIdx.x;
    const int lo = rowptr[b * 512];
    const int nhi = min((b + 1) * 512, NN);
    const int hi = rowptr[nhi];
    for (int i = lo + threadIdx.x; i < hi; i += 256) {
        unsigned int p = ebuf[i];
        int s = (int)(p & 0xFFFFu);
        int d = (int)(p >> 16);
        int pos = atomicAdd(&cursor[d], 1);
        csr[pos] = s;
    }
}

// ================= converts =================
// chunked layout: [chunk][node][32 shorts], chunk = feature>>5
__global__ __launch_bounds__(256) void cvt_x_kernel(const float* __restrict__ x,
                                                    unsigned short* __restrict__ xb) {
    int e = blockIdx.x * 256 + threadIdx.x;  // NPAD*64
    if (e >= NPAD * FIN) return;
    int n = e >> 6, k = e & 63;
    unsigned short v = (n < NN) ? bf16r(x[n * FIN + k]) : (unsigned short)0;
    xb[(size_t)(k >> 5) * (NPAD * 32) + n * 32 + (k & 31)] = v;
}

// all four weight transposes in one launch. Wt[n*K+k] = bf16(W[k*H+n])
__global__ __launch_bounds__(256) void cvt_w_all_kernel(const float* __restrict__ W1,
                                                        const float* __restrict__ W2,
                                                        const float* __restrict__ W3,
                                                        const float* __restrict__ W4,
                                                        unsigned short* __restrict__ Wt1,
                                                        unsigned short* __restrict__ Wt2,
                                                        unsigned short* __restrict__ Wt3,
                                                        unsigned short* __restrict__ Wt4) {
    int t = blockIdx.x * 256 + threadIdx.x;
    if (t < H * FIN) {
        int n = t / FIN, k = t % FIN;
        Wt1[t] = bf16r(W1[k * H + n]);
        return;
    }
    int u = t - H * FIN;
    const float* W = W2;
    unsigned short* Wt = Wt2;
    if (u >= 2 * H * H) { W = W4; Wt = Wt4; u -= 2 * H * H; }
    else if (u >= H * H) { W = W3; Wt = Wt3; u -= H * H; }
    if (u < H * H) {
        int n = u / H, k = u % H;
        Wt[u] = bf16r(W[k * H + n]);
    }
}

// ===== MFMA GEMM (chunked in/out): hw' = (h @ W) * dinv[row], bf16 out =====
// input chunk ks == K-slice ks (32 feats); output chunk = ct>>1.
template <int K>
__global__ __launch_bounds__(256) void gemm_mfma_kernel(const unsigned short* __restrict__ hb,
                                                        const unsigned short* __restrict__ Wt,
                                                        const float* __restrict__ dinv,
                                                        unsigned short* __restrict__ out) {
    const int wave = threadIdx.x >> 6, lane = threadIdx.x & 63;
    const int m15 = lane & 15, quad = lane >> 4;
    const int arow = blockIdx.x * 64 + wave * 16 + m15;

    bf16x8 a[K / 32];
#pragma unroll
    for (int ks = 0; ks < K / 32; ks++)
        a[ks] = *(const bf16x8*)&hb[(size_t)ks * (NPAD * 32) + arow * 32 + quad * 8];

    const int rbase = blockIdx.x * 64 + wave * 16 + quad * 4;
    float dv[4];
#pragma unroll
    for (int r = 0; r < 4; r++) dv[r] = dinv[rbase + r];

#pragma unroll
    for (int ct = 0; ct < 8; ct++) {
        f32x4 acc = {0.f, 0.f, 0.f, 0.f};
#pragma unroll
        for (int ks = 0; ks < K / 32; ks++) {
            bf16x8 b = *(const bf16x8*)&Wt[(ct * 16 + m15) * K + ks * 32 + quad * 8];
            acc = __builtin_amdgcn_mfma_f32_16x16x32_bf16(a[ks], b, acc, 0, 0, 0);
        }
#pragma unroll
        for (int r = 0; r < 4; r++)
            out[(size_t)(ct >> 1) * (NPAD * 32) + (rbase + r) * 32 + (ct & 1) * 16 + m15] =
                bf16r(acc[r] * dv[r]);
    }
}

// ============ feature-chunked gather aggregation ============
// grid: chunk-major, 4 chunks x NN/4 blocks; wave = one node's 32-feat slice.
// lane = (edge group g = lane>>4) x (uint u = lane&15); 4 edges per mem op;
// cross-group reduce via shfl_xor(16/32). Slice (3.2 MB) is L2-resident.
template <bool RELU_BIAS>
__global__ __launch_bounds__(256) void agg_kernel(const unsigned int* __restrict__ hwc,
                                                  const int* __restrict__ rowptr,
                                                  const int* __restrict__ csr,
                                                  const float* __restrict__ dinv,
                                                  const float* __restrict__ bias,
                                                  unsigned int* __restrict__ outc) {
    const int chunk = blockIdx.x / (NN / 4);
    const int nb = blockIdx.x % (NN / 4);
    const int wave = threadIdx.x >> 6, lane = threadIdx.x & 63;
    const int n = nb * 4 + wave;
    const int g = lane >> 4, u = lane & 15;
    const unsigned int* __restrict__ slice = hwc + (size_t)chunk * (NPAD * CHUNK_U);

    float ax = 0.f, ay = 0.f;
    const int beg = rowptr[n], end = rowptr[n + 1];
    int i = beg + g;
    for (; i + 4 < end; i += 8) {  // 2 edges per group per iter (ILP)
        int s0 = csr[i], s1 = csr[i + 4];
        unsigned int v0 = slice[s0 * CHUNK_U + u];
        unsigned int v1 = slice[s1 * CHUNK_U + u];
        ax += bf_lo(v0) + bf_lo(v1);
        ay += bf_hi(v0) + bf_hi(v1);
    }
    if (i < end) {
        int s = csr[i];
        unsigned int v = slice[s * CHUNK_U + u];
        ax += bf_lo(v);
        ay += bf_hi(v);
    }
    // reduce the 4 edge groups
    ax += __shfl_xor(ax, 16); ay += __shfl_xor(ay, 16);
    ax += __shfl_xor(ax, 32); ay += __shfl_xor(ay, 32);

    if (lane < 16) {
        unsigned int sv = slice[n * CHUNK_U + u];  // self-loop term
        float d = dinv[n];
        ax = (ax + bf_lo(sv)) * d;
        ay = (ay + bf_hi(sv)) * d;
        if (RELU_BIAS) {
            float2 bv = ((const float2*)bias)[chunk * CHUNK_U + u];
            ax = fmaxf(ax + bv.x, 0.f);
            ay = fmaxf(ay + bv.y, 0.f);
        }
        outc[(size_t)chunk * (NPAD * CHUNK_U) + n * CHUNK_U + u] = pack_bf16x2(ax, ay);
    }
}

// ======== pooling: block-local segment reduction (batch sorted), chunked bf16 in ========
__global__ __launch_bounds__(256) void pool_kernel(const unsigned int* __restrict__ hbu,
                                                   const float* __restrict__ b4,
                                                   const int* __restrict__ batch,
                                                   float* __restrict__ pooled,
                                                   float* __restrict__ cnt) {
    __shared__ int bs[POOL_NODES];
    const int tid = threadIdx.x;
    const int n0 = blockIdx.x * POOL_NODES;
    for (int i = tid; i < POOL_NODES; i += 256) bs[i] = batch[n0 + i];
    __syncthreads();
    const int c2 = tid & 63;                 // feature-uint index 0..63
    const int chunk = c2 >> 4, u = c2 & 15;
    const int rsub = tid >> 6;  // 0..3
    float2 bb = ((const float2*)b4)[c2];
    float2 acc = {0.f, 0.f};
    float cacc = 0.f;
    int curg = bs[rsub];
    const size_t coff = (size_t)chunk * (NPAD * CHUNK_U) + u;
    for (int r = rsub; r < POOL_NODES; r += 4) {
        int g = bs[r];
        if (g != curg) {
            atomicAdd(&pooled[curg * H + c2 * 2], acc.x);
            atomicAdd(&pooled[curg * H + c2 * 2 + 1], acc.y);
            if (c2 == 0) atomicAdd(&cnt[curg], cacc);
            acc.x = acc.y = 0.f;
            cacc = 0.f;
            curg = g;
        }
        unsigned int v = hbu[coff + (size_t)(n0 + r) * CHUNK_U];
        acc.x += bf_lo(v) + bb.x;
        acc.y += bf_hi(v) + bb.y;
        cacc += 1.f;
    }
    atomicAdd(&pooled[curg * H + c2 * 2], acc.x);
    atomicAdd(&pooled[curg * H + c2 * 2 + 1], acc.y);
    if (c2 == 0) atomicAdd(&cnt[curg], cacc);
}

// ================= final MLP (single block) =================
__global__ __launch_bounds__(1024) void mlp_kernel(const float* __restrict__ pooled,
                                                   const float* __restrict__ cnt,
                                                   const float* __restrict__ lw1,
                                                   const float* __restrict__ lb1,
                                                   const float* __restrict__ lw2,
                                                   const float* __restrict__ lb2,
                                                   float* __restrict__ out) {
    __shared__ float mean_s[NG * H];
    __shared__ float hid_s[NG * 64];
    int tid = threadIdx.x;
    for (int i = tid; i < NG * H; i += 1024) {
        int g = i >> 7;
        mean_s[i] = pooled[i] / fmaxf(cnt[g], 1.0f);
    }
    __syncthreads();
    {
        int g = tid >> 6, j = tid & 63;
        float acc = lb1[j];
        for (int f = 0; f < H; f++) acc += mean_s[g * H + f] * lw1[f * 64 + j];
        hid_s[g * 64 + j] = fmaxf(acc, 0.f);
    }
    __syncthreads();
    if (tid < 32) {
        int g = tid >> 1, c = tid & 1;
        float acc = lb2[c];
        for (int j = 0; j < 64; j++) acc += hid_s[g * 64 + j] * lw2[j * 2 + c];
        out[g * 2 + c] = acc;
    }
}

extern "C" void kernel_launch(void* const* d_in, const int* in_sizes, int n_in,
                              void* d_out, int out_size, void* d_ws, size_t ws_size,
                              hipStream_t stream) {
    const float* x = (const float*)d_in[0];
    const int* ei = (const int*)d_in[1];
    const int* batch = (const int*)d_in[2];
    const float* W1 = (const float*)d_in[3];
    const float* b1 = (const float*)d_in[4];
    const float* W2 = (const float*)d_in[5];
    const float* b2 = (const float*)d_in[6];
    const float* W3 = (const float*)d_in[7];
    const float* b3 = (const float*)d_in[8];
    const float* W4 = (const float*)d_in[9];
    const float* b4 = (const float*)d_in[10];
    const float* lw1 = (const float*)d_in[11];
    const float* lb1 = (const float*)d_in[12];
    const float* lw2 = (const float*)d_in[13];
    const float* lb2 = (const float*)d_in[14];
    float* out = (float*)d_out;

    // workspace layout (4-byte units); total ~40 MB
    int* wsi = (int*)d_ws;
    int* cnt = wsi;                                        // 50048
    int* bsum = wsi + 50048;                               // 256
    int* rowptr = wsi + 50304;                             // 50016
    int* cursor = wsi + 100320;                            // 50048
    int* csr = wsi + 150368;                               // NE
    float* dinv = (float*)(wsi + 950368);                  // 50048
    unsigned short* Wt1 = (unsigned short*)(wsi + 1000416);  // 128*64
    unsigned short* Wt2 = (unsigned short*)(wsi + 1004512);  // 128*128
    unsigned short* Wt3 = (unsigned short*)(wsi + 1012704);
    unsigned short* Wt4 = (unsigned short*)(wsi + 1020896);
    unsigned short* xb = (unsigned short*)(wsi + 1029088);   // NPAD*64 (chunked)
    unsigned int* hb = (unsigned int*)(wsi + 2630624);       // NPAD*64 (chunked bf16x2)
    unsigned int* hwb = (unsigned int*)(wsi + 5833696);      // NPAD*64 (chunked bf16x2)
    float* pooled = (float*)(wsi + 9036768);                 // NG*H
    float* pcnt = pooled + NG * H;                           // NG
    int* gbase = wsi + 9038928;                              // 128
    unsigned int* ebuf = (unsigned int*)(wsi + 9039056);     // NE

    const int edgeBlocks = (NE + 255) / 256;   // 3125
    const int gemmBlocks = NPAD / 64;          // 782
    const int aggBlocks = 4 * (NN / 4);        // 50000, chunk-major

    // ---- CSR build (once; reused by all 4 layers) ----
    hipMemsetAsync(cnt, 0, NN * sizeof(int), stream);
    hist_kernel<<<edgeBlocks, 256, 0, stream>>>(ei + NE, cnt);
    scanA_kernel<<<SCAN_BLOCKS, 256, 0, stream>>>(cnt, bsum);
    scanB_kernel<<<1, 256, 0, stream>>>(bsum);
    scanC_kernel<<<SCAN_BLOCKS, 256, 0, stream>>>(cnt, bsum, rowptr, cursor, dinv, gbase);
    fillA_kernel<<<FILLA_BLOCKS, 256, 0, stream>>>(ei, gbase, ebuf);
    fillB_kernel<<<NBUCK, 256, 0, stream>>>(ebuf, rowptr, cursor, csr);

    // ---- converts ----
    cvt_x_kernel<<<(NPAD * FIN) / 256, 256, 0, stream>>>(x, xb);
    cvt_w_all_kernel<<<(H * FIN + 3 * H * H) / 256, 256, 0, stream>>>(
        W1, W2, W3, W4, Wt1, Wt2, Wt3, Wt4);

    // ---- layer 1 ----
    gemm_mfma_kernel<FIN><<<gemmBlocks, 256, 0, stream>>>(xb, Wt1, dinv, (unsigned short*)hwb);
    agg_kernel<true><<<aggBlocks, 256, 0, stream>>>(hwb, rowptr, csr, dinv, b1, hb);
    // ---- layer 2 ----
    gemm_mfma_kernel<H><<<gemmBlocks, 256, 0, stream>>>((unsigned short*)hb, Wt2, dinv, (unsigned short*)hwb);
    agg_kernel<true><<<aggBlocks, 256, 0, stream>>>(hwb, rowptr, csr, dinv, b2, hb);
    // ---- layer 3 ----
    gemm_mfma_kernel<H><<<gemmBlocks, 256, 0, stream>>>((unsigned short*)hb, Wt3, dinv, (unsigned short*)hwb);
    agg_kernel<true><<<aggBlocks, 256, 0, stream>>>(hwb, rowptr, csr, dinv, b3, hb);
    // ---- layer 4 (no relu/bias; b4 fused in pool) ----
    gemm_mfma_kernel<H><<<gemmBlocks, 256, 0, stream>>>((unsigned short*)hb, Wt4, dinv, (unsigned short*)hwb);
    agg_kernel<false><<<aggBlocks, 256, 0, stream>>>(hwb, rowptr, csr, dinv, nullptr, hb);

    // ---- pooling (fused +b4) + MLP ----
    hipMemsetAsync(pooled, 0, (NG * H + NG) * sizeof(float), stream);
    pool_kernel<<<POOL_BLOCKS, 256, 0, stream>>>(hb, b4, batch, pooled, pcnt);
    mlp_kernel<<<1, 1024, 0, stream>>>(pooled, pcnt, lw1, lb1, lw2, lb2, out);
}

// Round 9
// 488.604 us; speedup vs baseline: 1.2590x; 1.2590x over previous
//
#include <hip/hip_runtime.h>

#define NN 50000
#define NPAD 50048   // rows padded to multiple of 64 for MFMA tiles
#define NE 800000
#define FIN 64
#define H 128
#define NG 16
#define POOL_BLOCKS 200
#define POOL_NODES 250
#define SCAN_BLOCKS 196  // ceil(NN/256)
#define NBUCK 98         // buckets of 512 dst nodes
#define FILLA_BLOCKS 64
#define FILLA_CHUNK (NE / FILLA_BLOCKS)  // 12500
#define CHUNK_U 16       // uints per node per feature-chunk (32 feats)

typedef __bf16 bf16x8 __attribute__((ext_vector_type(8)));
typedef float f32x4 __attribute__((ext_vector_type(4)));

// ---- helpers ----
__device__ inline unsigned short bf16r(float x) {
    unsigned int u = __float_as_uint(x);
    return (unsigned short)((u + 0x7fffu + ((u >> 16) & 1u)) >> 16);
}
__device__ inline unsigned int pack_bf16x2(float a, float b) {
    return (unsigned int)bf16r(a) | ((unsigned int)bf16r(b) << 16);
}
__device__ inline float bf_lo(unsigned int u) { return __uint_as_float(u << 16); }
__device__ inline float bf_hi(unsigned int u) { return __uint_as_float(u & 0xffff0000u); }

// ================= CSR build =================
__global__ __launch_bounds__(256) void hist_kernel(const int* __restrict__ dst,
                                                   int* __restrict__ cnt) {
    int e = blockIdx.x * 256 + threadIdx.x;
    if (e < NE) atomicAdd(&cnt[dst[e]], 1);
}

__global__ __launch_bounds__(256) void scanA_kernel(const int* __restrict__ cnt,
                                                    int* __restrict__ bsum) {
    __shared__ int red[4];
    int i = blockIdx.x * 256 + threadIdx.x;
    int v = (i < NN) ? cnt[i] : 0;
    for (int off = 32; off > 0; off >>= 1) v += __shfl_down(v, off);
    if ((threadIdx.x & 63) == 0) red[threadIdx.x >> 6] = v;
    __syncthreads();
    if (threadIdx.x == 0) bsum[blockIdx.x] = red[0] + red[1] + red[2] + red[3];
}

__global__ __launch_bounds__(256) void scanB_kernel(int* __restrict__ bsum) {
    __shared__ int s[256];
    int t = threadIdx.x;
    int v = (t < SCAN_BLOCKS) ? bsum[t] : 0;
    s[t] = v;
    __syncthreads();
    for (int off = 1; off < 256; off <<= 1) {
        int u = (t >= off) ? s[t - off] : 0;
        __syncthreads();
        s[t] += u;
        __syncthreads();
    }
    if (t < SCAN_BLOCKS) bsum[t] = s[t] - v;  // exclusive
}

// scanC: rowptr/cursor + dinv + bucket bases (gbase[b] = rowptr[b*512])
__global__ __launch_bounds__(256) void scanC_kernel(const int* __restrict__ cnt,
                                                    const int* __restrict__ bsum,
                                                    int* __restrict__ rowptr,
                                                    int* __restrict__ cursor,
                                                    float* __restrict__ dinv,
                                                    int* __restrict__ gbase) {
    __shared__ int s[256];
    int t = threadIdx.x;
    int i = blockIdx.x * 256 + t;
    int v = (i < NN) ? cnt[i] : 0;
    s[t] = v;
    __syncthreads();
    for (int off = 1; off < 256; off <<= 1) {
        int u = (t >= off) ? s[t - off] : 0;
        __syncthreads();
        s[t] += u;
        __syncthreads();
    }
    if (i < NN) {
        int ex = bsum[blockIdx.x] + s[t] - v;
        rowptr[i] = ex;
        cursor[i] = ex;
        dinv[i] = rsqrtf((float)v + 1.0f);  // +1 self-loop
        if ((i & 511) == 0) gbase[i >> 9] = ex;
    }
    if (i == NN - 1) rowptr[NN] = NE;
}

// fillA: bucket edges by dst>>9 (contiguous appends -> merged writebacks)
__global__ __launch_bounds__(256) void fillA_kernel(const int* __restrict__ ei,
                                                    int* __restrict__ gbase,
                                                    unsigned int* __restrict__ ebuf) {
    __shared__ int hist[128];
    __shared__ int base[128];
    const int t = threadIdx.x;
    if (t < 128) hist[t] = 0;
    __syncthreads();
    const int e0 = blockIdx.x * FILLA_CHUNK;
    for (int e = e0 + t; e < e0 + FILLA_CHUNK; e += 256)
        atomicAdd(&hist[ei[NE + e] >> 9], 1);
    __syncthreads();
    if (t < 128) {
        int h = (t < NBUCK) ? hist[t] : 0;
        base[t] = h ? atomicAdd(&gbase[t], h) : 0;
    }
    __syncthreads();
    for (int e = e0 + t; e < e0 + FILLA_CHUNK; e += 256) {
        int d = ei[NE + e];
        int s = ei[e];
        int pos = atomicAdd(&base[d >> 9], 1);
        ebuf[pos] = (unsigned int)s | ((unsigned int)d << 16);
    }
}

// fillB: one block per bucket; scatter within the bucket's csr window
__global__ __launch_bounds__(256) void fillB_kernel(const unsigned int* __restrict__ ebuf,
                                                    const int* __restrict__ rowptr,
                                                    int* __restrict__ cursor,
                                                    int* __restrict__ csr) {
    const int b = blockIdx.x;
    const int lo = rowptr[b * 512];
    const int nhi = min((b + 1) * 512, NN);
    const int hi = rowptr[nhi];
    for (int i = lo + threadIdx.x; i < hi; i += 256) {
        unsigned int p = ebuf[i];
        int s = (int)(p & 0xFFFFu);
        int d = (int)(p >> 16);
        int pos = atomicAdd(&cursor[d], 1);
        csr[pos] = s;
    }
}

// ================= converts =================
// chunked layout: [chunk][node][32 shorts], chunk = feature>>5
__global__ __launch_bounds__(256) void cvt_x_kernel(const float* __restrict__ x,
                                                    unsigned short* __restrict__ xb) {
    int e = blockIdx.x * 256 + threadIdx.x;  // NPAD*64
    if (e >= NPAD * FIN) return;
    int n = e >> 6, k = e & 63;
    unsigned short v = (n < NN) ? bf16r(x[n * FIN + k]) : (unsigned short)0;
    xb[(size_t)(k >> 5) * (NPAD * 32) + n * 32 + (k & 31)] = v;
}

// all four weight transposes in one launch. Wt[n*K+k] = bf16(W[k*H+n])
__global__ __launch_bounds__(256) void cvt_w_all_kernel(const float* __restrict__ W1,
                                                        const float* __restrict__ W2,
                                                        const float* __restrict__ W3,
                                                        const float* __restrict__ W4,
                                                        unsigned short* __restrict__ Wt1,
                                                        unsigned short* __restrict__ Wt2,
                                                        unsigned short* __restrict__ Wt3,
                                                        unsigned short* __restrict__ Wt4) {
    int t = blockIdx.x * 256 + threadIdx.x;
    if (t < H * FIN) {
        int n = t / FIN, k = t % FIN;
        Wt1[t] = bf16r(W1[k * H + n]);
        return;
    }
    int u = t - H * FIN;
    const float* W = W2;
    unsigned short* Wt = Wt2;
    if (u >= 2 * H * H) { W = W4; Wt = Wt4; u -= 2 * H * H; }
    else if (u >= H * H) { W = W3; Wt = Wt3; u -= H * H; }
    if (u < H * H) {
        int n = u / H, k = u % H;
        Wt[u] = bf16r(W[k * H + n]);
    }
}

// ===== MFMA GEMM (chunked in/out): hw' = (h @ W) * dinv[row], bf16 out =====
// input chunk ks == K-slice ks (32 feats); output chunk = ct>>1.
template <int K>
__global__ __launch_bounds__(256) void gemm_mfma_kernel(const unsigned short* __restrict__ hb,
                                                        const unsigned short* __restrict__ Wt,
                                                        const float* __restrict__ dinv,
                                                        unsigned short* __restrict__ out) {
    const int wave = threadIdx.x >> 6, lane = threadIdx.x & 63;
    const int m15 = lane & 15, quad = lane >> 4;
    const int arow = blockIdx.x * 64 + wave * 16 + m15;

    bf16x8 a[K / 32];
#pragma unroll
    for (int ks = 0; ks < K / 32; ks++)
        a[ks] = *(const bf16x8*)&hb[(size_t)ks * (NPAD * 32) + arow * 32 + quad * 8];

    const int rbase = blockIdx.x * 64 + wave * 16 + quad * 4;
    float dv[4];
#pragma unroll
    for (int r = 0; r < 4; r++) dv[r] = dinv[rbase + r];

#pragma unroll
    for (int ct = 0; ct < 8; ct++) {
        f32x4 acc = {0.f, 0.f, 0.f, 0.f};
#pragma unroll
        for (int ks = 0; ks < K / 32; ks++) {
            bf16x8 b = *(const bf16x8*)&Wt[(ct * 16 + m15) * K + ks * 32 + quad * 8];
            acc = __builtin_amdgcn_mfma_f32_16x16x32_bf16(a[ks], b, acc, 0, 0, 0);
        }
#pragma unroll
        for (int r = 0; r < 4; r++)
            out[(size_t)(ct >> 1) * (NPAD * 32) + (rbase + r) * 32 + (ct & 1) * 16 + m15] =
                bf16r(acc[r] * dv[r]);
    }
}

// ============ feature-chunked gather aggregation, node-per-group ============
// grid chunk-major: 4 chunks x NN/16 blocks. Block = 16 nodes; wave = 4 nodes;
// 16-lane group g owns node nb*16 + wave*4 + g and walks its edge list with an
// 8-deep unroll -> 8 load instrs x (4 groups x 64 B) = 2 KB in flight per wave,
// all inside the 3.2 MB L2-resident chunk slice. No cross-group reduction.
template <bool RELU_BIAS>
__global__ __launch_bounds__(256) void agg_kernel(const unsigned int* __restrict__ hwc,
                                                  const int* __restrict__ rowptr,
                                                  const int* __restrict__ csr,
                                                  const float* __restrict__ dinv,
                                                  const float* __restrict__ bias,
                                                  unsigned int* __restrict__ outc) {
    const int chunk = blockIdx.x / (NN / 16);
    const int nb = blockIdx.x % (NN / 16);
    const int wave = threadIdx.x >> 6, lane = threadIdx.x & 63;
    const int g = lane >> 4, u = lane & 15;
    const int n = nb * 16 + wave * 4 + g;
    const unsigned int* __restrict__ slice = hwc + (size_t)chunk * (NPAD * CHUNK_U);

    unsigned int sv = slice[n * CHUNK_U + u];  // self-loop term
    float ax = bf_lo(sv), ay = bf_hi(sv);

    const int beg = rowptr[n], end = rowptr[n + 1];
    int i = beg;
    for (; i + 8 <= end; i += 8) {
        int s0 = csr[i],     s1 = csr[i + 1], s2 = csr[i + 2], s3 = csr[i + 3];
        int s4 = csr[i + 4], s5 = csr[i + 5], s6 = csr[i + 6], s7 = csr[i + 7];
        unsigned int v0 = slice[s0 * CHUNK_U + u], v1 = slice[s1 * CHUNK_U + u];
        unsigned int v2 = slice[s2 * CHUNK_U + u], v3 = slice[s3 * CHUNK_U + u];
        unsigned int v4 = slice[s4 * CHUNK_U + u], v5 = slice[s5 * CHUNK_U + u];
        unsigned int v6 = slice[s6 * CHUNK_U + u], v7 = slice[s7 * CHUNK_U + u];
        ax += bf_lo(v0) + bf_lo(v1) + bf_lo(v2) + bf_lo(v3) +
              bf_lo(v4) + bf_lo(v5) + bf_lo(v6) + bf_lo(v7);
        ay += bf_hi(v0) + bf_hi(v1) + bf_hi(v2) + bf_hi(v3) +
              bf_hi(v4) + bf_hi(v5) + bf_hi(v6) + bf_hi(v7);
    }
    for (; i < end; i++) {
        unsigned int v = slice[csr[i] * CHUNK_U + u];
        ax += bf_lo(v);
        ay += bf_hi(v);
    }

    float d = dinv[n];
    ax *= d;
    ay *= d;
    if (RELU_BIAS) {
        float2 bv = ((const float2*)bias)[chunk * CHUNK_U + u];
        ax = fmaxf(ax + bv.x, 0.f);
        ay = fmaxf(ay + bv.y, 0.f);
    }
    outc[(size_t)chunk * (NPAD * CHUNK_U) + n * CHUNK_U + u] = pack_bf16x2(ax, ay);
}

// ======== pooling: block-local segment reduction (batch sorted), chunked bf16 in ========
__global__ __launch_bounds__(256) void pool_kernel(const unsigned int* __restrict__ hbu,
                                                   const float* __restrict__ b4,
                                                   const int* __restrict__ batch,
                                                   float* __restrict__ pooled,
                                                   float* __restrict__ cnt) {
    __shared__ int bs[POOL_NODES];
    const int tid = threadIdx.x;
    const int n0 = blockIdx.x * POOL_NODES;
    for (int i = tid; i < POOL_NODES; i += 256) bs[i] = batch[n0 + i];
    __syncthreads();
    const int c2 = tid & 63;                 // feature-uint index 0..63
    const int chunk = c2 >> 4, u = c2 & 15;
    const int rsub = tid >> 6;  // 0..3
    float2 bb = ((const float2*)b4)[c2];
    float2 acc = {0.f, 0.f};
    float cacc = 0.f;
    int curg = bs[rsub];
    const size_t coff = (size_t)chunk * (NPAD * CHUNK_U) + u;
    for (int r = rsub; r < POOL_NODES; r += 4) {
        int g = bs[r];
        if (g != curg) {
            atomicAdd(&pooled[curg * H + c2 * 2], acc.x);
            atomicAdd(&pooled[curg * H + c2 * 2 + 1], acc.y);
            if (c2 == 0) atomicAdd(&cnt[curg], cacc);
            acc.x = acc.y = 0.f;
            cacc = 0.f;
            curg = g;
        }
        unsigned int v = hbu[coff + (size_t)(n0 + r) * CHUNK_U];
        acc.x += bf_lo(v) + bb.x;
        acc.y += bf_hi(v) + bb.y;
        cacc += 1.f;
    }
    atomicAdd(&pooled[curg * H + c2 * 2], acc.x);
    atomicAdd(&pooled[curg * H + c2 * 2 + 1], acc.y);
    if (c2 == 0) atomicAdd(&cnt[curg], cacc);
}

// ================= final MLP (single block) =================
__global__ __launch_bounds__(1024) void mlp_kernel(const float* __restrict__ pooled,
                                                   const float* __restrict__ cnt,
                                                   const float* __restrict__ lw1,
                                                   const float* __restrict__ lb1,
                                                   const float* __restrict__ lw2,
                                                   const float* __restrict__ lb2,
                                                   float* __restrict__ out) {
    __shared__ float mean_s[NG * H];
    __shared__ float hid_s[NG * 64];
    int tid = threadIdx.x;
    for (int i = tid; i < NG * H; i += 1024) {
        int g = i >> 7;
        mean_s[i] = pooled[i] / fmaxf(cnt[g], 1.0f);
    }
    __syncthreads();
    {
        int g = tid >> 6, j = tid & 63;
        float acc = lb1[j];
        for (int f = 0; f < H; f++) acc += mean_s[g * H + f] * lw1[f * 64 + j];
        hid_s[g * 64 + j] = fmaxf(acc, 0.f);
    }
    __syncthreads();
    if (tid < 32) {
        int g = tid >> 1, c = tid & 1;
        float acc = lb2[c];
        for (int j = 0; j < 64; j++) acc += hid_s[g * 64 + j] * lw2[j * 2 + c];
        out[g * 2 + c] = acc;
    }
}

extern "C" void kernel_launch(void* const* d_in, const int* in_sizes, int n_in,
                              void* d_out, int out_size, void* d_ws, size_t ws_size,
                              hipStream_t stream) {
    const float* x = (const float*)d_in[0];
    const int* ei = (const int*)d_in[1];
    const int* batch = (const int*)d_in[2];
    const float* W1 = (const float*)d_in[3];
    const float* b1 = (const float*)d_in[4];
    const float* W2 = (const float*)d_in[5];
    const float* b2 = (const float*)d_in[6];
    const float* W3 = (const float*)d_in[7];
    const float* b3 = (const float*)d_in[8];
    const float* W4 = (const float*)d_in[9];
    const float* b4 = (const float*)d_in[10];
    const float* lw1 = (const float*)d_in[11];
    const float* lb1 = (const float*)d_in[12];
    const float* lw2 = (const float*)d_in[13];
    const float* lb2 = (const float*)d_in[14];
    float* out = (float*)d_out;

    // workspace layout (4-byte units); total ~40 MB
    int* wsi = (int*)d_ws;
    int* cnt = wsi;                                        // 50048
    int* bsum = wsi + 50048;                               // 256
    int* rowptr = wsi + 50304;                             // 50016
    int* cursor = wsi + 100320;                            // 50048
    int* csr = wsi + 150368;                               // NE
    float* dinv = (float*)(wsi + 950368);                  // 50048
    unsigned short* Wt1 = (unsigned short*)(wsi + 1000416);  // 128*64
    unsigned short* Wt2 = (unsigned short*)(wsi + 1004512);  // 128*128
    unsigned short* Wt3 = (unsigned short*)(wsi + 1012704);
    unsigned short* Wt4 = (unsigned short*)(wsi + 1020896);
    unsigned short* xb = (unsigned short*)(wsi + 1029088);   // NPAD*64 (chunked)
    unsigned int* hb = (unsigned int*)(wsi + 2630624);       // NPAD*64 (chunked bf16x2)
    unsigned int* hwb = (unsigned int*)(wsi + 5833696);      // NPAD*64 (chunked bf16x2)
    float* pooled = (float*)(wsi + 9036768);                 // NG*H
    float* pcnt = pooled + NG * H;                           // NG
    int* gbase = wsi + 9038928;                              // 128
    unsigned int* ebuf = (unsigned int*)(wsi + 9039056);     // NE

    const int edgeBlocks = (NE + 255) / 256;   // 3125
    const int gemmBlocks = NPAD / 64;          // 782
    const int aggBlocks = 4 * (NN / 16);       // 12500, chunk-major

    // ---- CSR build (once; reused by all 4 layers) ----
    hipMemsetAsync(cnt, 0, NN * sizeof(int), stream);
    hist_kernel<<<edgeBlocks, 256, 0, stream>>>(ei + NE, cnt);
    scanA_kernel<<<SCAN_BLOCKS, 256, 0, stream>>>(cnt, bsum);
    scanB_kernel<<<1, 256, 0, stream>>>(bsum);
    scanC_kernel<<<SCAN_BLOCKS, 256, 0, stream>>>(cnt, bsum, rowptr, cursor, dinv, gbase);
    fillA_kernel<<<FILLA_BLOCKS, 256, 0, stream>>>(ei, gbase, ebuf);
    fillB_kernel<<<NBUCK, 256, 0, stream>>>(ebuf, rowptr, cursor, csr);

    // ---- converts ----
    cvt_x_kernel<<<(NPAD * FIN) / 256, 256, 0, stream>>>(x, xb);
    cvt_w_all_kernel<<<(H * FIN + 3 * H * H) / 256, 256, 0, stream>>>(
        W1, W2, W3, W4, Wt1, Wt2, Wt3, Wt4);

    // ---- layer 1 ----
    gemm_mfma_kernel<FIN><<<gemmBlocks, 256, 0, stream>>>(xb, Wt1, dinv, (unsigned short*)hwb);
    agg_kernel<true><<<aggBlocks, 256, 0, stream>>>(hwb, rowptr, csr, dinv, b1, hb);
    // ---- layer 2 ----
    gemm_mfma_kernel<H><<<gemmBlocks, 256, 0, stream>>>((unsigned short*)hb, Wt2, dinv, (unsigned short*)hwb);
    agg_kernel<true><<<aggBlocks, 256, 0, stream>>>(hwb, rowptr, csr, dinv, b2, hb);
    // ---- layer 3 ----
    gemm_mfma_kernel<H><<<gemmBlocks, 256, 0, stream>>>((unsigned short*)hb, Wt3, dinv, (unsigned short*)hwb);
    agg_kernel<true><<<aggBlocks, 256, 0, stream>>>(hwb, rowptr, csr, dinv, b3, hb);
    // ---- layer 4 (no relu/bias; b4 fused in pool) ----
    gemm_mfma_kernel<H><<<gemmBlocks, 256, 0, stream>>>((unsigned short*)hb, Wt4, dinv, (unsigned short*)hwb);
    agg_kernel<false><<<aggBlocks, 256, 0, stream>>>(hwb, rowptr, csr, dinv, nullptr, hb);

    // ---- pooling (fused +b4) + MLP ----
    hipMemsetAsync(pooled, 0, (NG * H + NG) * sizeof(float), stream);
    pool_kernel<<<POOL_BLOCKS, 256, 0, stream>>>(hb, b4, batch, pooled, pcnt);
    mlp_kernel<<<1, 1024, 0, stream>>>(pooled, pcnt, lw1, lb1, lw2, lb2, out);
}

// Round 10
// 438.400 us; speedup vs baseline: 1.4031x; 1.1145x over previous
//
#include <hip/hip_runtime.h>

#define NN 50000
#define NPAD 50048   // rows padded to multiple of 64 for MFMA tiles
#define NE 800000
#define FIN 64
#define H 128
#define NG 16
#define POOL_BLOCKS 200
#define POOL_NODES 250
#define SCAN_BLOCKS 196  // ceil(NN/256)
#define NBUCK 98         // buckets of 512 dst nodes
#define FILLA_BLOCKS 64
#define FILLA_CHUNK (NE / FILLA_BLOCKS)  // 12500
#define CHUNK_U 16       // uints per node per feature-chunk (32 feats)
#define CSR_CAP 1200000  // >= NE + 7*NN
#define DUMMY NN         // zero pad row used for CSR padding

typedef __bf16 bf16x8 __attribute__((ext_vector_type(8)));
typedef float f32x4 __attribute__((ext_vector_type(4)));

// ---- helpers ----
__device__ inline unsigned short bf16r(float x) {
    unsigned int u = __float_as_uint(x);
    return (unsigned short)((u + 0x7fffu + ((u >> 16) & 1u)) >> 16);
}
__device__ inline unsigned int pack_bf16x2(float a, float b) {
    return (unsigned int)bf16r(a) | ((unsigned int)bf16r(b) << 16);
}
__device__ inline float bf_lo(unsigned int u) { return __uint_as_float(u << 16); }
__device__ inline float bf_hi(unsigned int u) { return __uint_as_float(u & 0xffff0000u); }

// ================= CSR build =================
__global__ __launch_bounds__(256) void hist_kernel(const int* __restrict__ dst,
                                                   int* __restrict__ cnt) {
    int e = blockIdx.x * 256 + threadIdx.x;
    if (e < NE) atomicAdd(&cnt[dst[e]], 1);
}

// per-block sums of real and padded (to x8) counts
__global__ __launch_bounds__(256) void scanA_kernel(const int* __restrict__ cnt,
                                                    int* __restrict__ bsumR,
                                                    int* __restrict__ bsumP) {
    __shared__ int redR[4], redP[4];
    int i = blockIdx.x * 256 + threadIdx.x;
    int v = (i < NN) ? cnt[i] : 0;
    int p = (v + 7) & ~7;
    for (int off = 32; off > 0; off >>= 1) {
        v += __shfl_down(v, off);
        p += __shfl_down(p, off);
    }
    if ((threadIdx.x & 63) == 0) {
        redR[threadIdx.x >> 6] = v;
        redP[threadIdx.x >> 6] = p;
    }
    __syncthreads();
    if (threadIdx.x == 0) {
        bsumR[blockIdx.x] = redR[0] + redR[1] + redR[2] + redR[3];
        bsumP[blockIdx.x] = redP[0] + redP[1] + redP[2] + redP[3];
    }
}

// exclusive scan of both partial arrays
__global__ __launch_bounds__(256) void scanB_kernel(int* __restrict__ bsumR,
                                                    int* __restrict__ bsumP) {
    __shared__ int sR[256], sP[256];
    int t = threadIdx.x;
    int vR = (t < SCAN_BLOCKS) ? bsumR[t] : 0;
    int vP = (t < SCAN_BLOCKS) ? bsumP[t] : 0;
    sR[t] = vR; sP[t] = vP;
    __syncthreads();
    for (int off = 1; off < 256; off <<= 1) {
        int uR = (t >= off) ? sR[t - off] : 0;
        int uP = (t >= off) ? sP[t - off] : 0;
        __syncthreads();
        sR[t] += uR; sP[t] += uP;
        __syncthreads();
    }
    if (t < SCAN_BLOCKS) {
        bsumR[t] = sR[t] - vR;  // exclusive
        bsumP[t] = sP[t] - vP;
    }
}

// scanC: padded rowptr/cursor + dinv (real, 0 on pad rows) + real bucket bases
__global__ __launch_bounds__(256) void scanC_kernel(const int* __restrict__ cnt,
                                                    const int* __restrict__ bsumR,
                                                    const int* __restrict__ bsumP,
                                                    int* __restrict__ rowptr,
                                                    int* __restrict__ cursor,
                                                    float* __restrict__ dinv,
                                                    int* __restrict__ gbase) {
    __shared__ int sR[256], sP[256];
    int t = threadIdx.x;
    int i = blockIdx.x * 256 + t;
    int v = (i < NN) ? cnt[i] : 0;
    int p = (v + 7) & ~7;
    sR[t] = v; sP[t] = p;
    __syncthreads();
    for (int off = 1; off < 256; off <<= 1) {
        int uR = (t >= off) ? sR[t - off] : 0;
        int uP = (t >= off) ? sP[t - off] : 0;
        __syncthreads();
        sR[t] += uR; sP[t] += uP;
        __syncthreads();
    }
    if (i < NN) {
        int exP = bsumP[blockIdx.x] + sP[t] - p;
        rowptr[i] = exP;
        cursor[i] = exP;
        dinv[i] = rsqrtf((float)v + 1.0f);  // +1 self-loop
        if ((i & 511) == 0) gbase[i >> 9] = bsumR[blockIdx.x] + sR[t] - v;
        if (i == NN - 1) rowptr[NN] = exP + p;
    } else if (i < NPAD) {
        dinv[i] = 0.0f;  // pad rows: forces zero outputs through the chain
    }
}

// csr pre-init: every slot points at the zero dummy row
__global__ __launch_bounds__(256) void csr_init_kernel(int* __restrict__ csr) {
    int i = blockIdx.x * 256 + threadIdx.x;
    if (i < CSR_CAP) csr[i] = DUMMY;
}

// fillA: bucket edges by dst>>9 into compact ebuf (contiguous appends)
__global__ __launch_bounds__(256) void fillA_kernel(const int* __restrict__ ei,
                                                    int* __restrict__ gbase,
                                                    unsigned int* __restrict__ ebuf) {
    __shared__ int hist[128];
    __shared__ int base[128];
    const int t = threadIdx.x;
    if (t < 128) hist[t] = 0;
    __syncthreads();
    const int e0 = blockIdx.x * FILLA_CHUNK;
    for (int e = e0 + t; e < e0 + FILLA_CHUNK; e += 256)
        atomicAdd(&hist[ei[NE + e] >> 9], 1);
    __syncthreads();
    if (t < 128) {
        int h = (t < NBUCK) ? hist[t] : 0;
        base[t] = h ? atomicAdd(&gbase[t], h) : 0;
    }
    __syncthreads();
    for (int e = e0 + t; e < e0 + FILLA_CHUNK; e += 256) {
        int d = ei[NE + e];
        int s = ei[e];
        int pos = atomicAdd(&base[d >> 9], 1);
        ebuf[pos] = (unsigned int)s | ((unsigned int)d << 16);
    }
}

// fillB: one block per bucket; after fillA, gbase[b] = real prefix end of bucket b
__global__ __launch_bounds__(256) void fillB_kernel(const unsigned int* __restrict__ ebuf,
                                                    const int* __restrict__ gbase,
                                                    int* __restrict__ cursor,
                                                    int* __restrict__ csr) {
    const int b = blockIdx.x;
    const int lo = b ? gbase[b - 1] : 0;
    const int hi = gbase[b];
    for (int i = lo + threadIdx.x; i < hi; i += 256) {
        unsigned int p = ebuf[i];
        int s = (int)(p & 0xFFFFu);
        int d = (int)(p >> 16);
        int pos = atomicAdd(&cursor[d], 1);
        csr[pos] = s;
    }
}

// ================= converts =================
// chunked layout: [chunk][node][32 shorts], chunk = feature>>5
__global__ __launch_bounds__(256) void cvt_x_kernel(const float* __restrict__ x,
                                                    unsigned short* __restrict__ xb) {
    int e = blockIdx.x * 256 + threadIdx.x;  // NPAD*64
    if (e >= NPAD * FIN) return;
    int n = e >> 6, k = e & 63;
    unsigned short v = (n < NN) ? bf16r(x[n * FIN + k]) : (unsigned short)0;
    xb[(size_t)(k >> 5) * (NPAD * 32) + n * 32 + (k & 31)] = v;
}

// zero the pad rows of hb (never written by agg; read by layer 2+ gemm)
__global__ __launch_bounds__(256) void pad_zero_kernel(unsigned int* __restrict__ hb) {
    int t = blockIdx.x * 256 + threadIdx.x;  // 4 chunks * 48 rows * 16 uints = 3072
    if (t >= 4 * (NPAD - NN) * CHUNK_U) return;
    int chunk = t / ((NPAD - NN) * CHUNK_U);
    int r = t % ((NPAD - NN) * CHUNK_U);
    hb[(size_t)chunk * (NPAD * CHUNK_U) + (size_t)NN * CHUNK_U + r] = 0u;
}

// all four weight transposes in one launch. Wt[n*K+k] = bf16(W[k*H+n])
__global__ __launch_bounds__(256) void cvt_w_all_kernel(const float* __restrict__ W1,
                                                        const float* __restrict__ W2,
                                                        const float* __restrict__ W3,
                                                        const float* __restrict__ W4,
                                                        unsigned short* __restrict__ Wt1,
                                                        unsigned short* __restrict__ Wt2,
                                                        unsigned short* __restrict__ Wt3,
                                                        unsigned short* __restrict__ Wt4) {
    int t = blockIdx.x * 256 + threadIdx.x;
    if (t < H * FIN) {
        int n = t / FIN, k = t % FIN;
        Wt1[t] = bf16r(W1[k * H + n]);
        return;
    }
    int u = t - H * FIN;
    const float* W = W2;
    unsigned short* Wt = Wt2;
    if (u >= 2 * H * H) { W = W4; Wt = Wt4; u -= 2 * H * H; }
    else if (u >= H * H) { W = W3; Wt = Wt3; u -= H * H; }
    if (u < H * H) {
        int n = u / H, k = u % H;
        Wt[u] = bf16r(W[k * H + n]);
    }
}

// ===== MFMA GEMM (chunked in/out): hw' = (h @ W) * dinv[row], bf16 out =====
// Epilogue goes through LDS: fp32 tile staged, then packed uint4 coalesced stores.
#define LSTRIDE 130
template <int K>
__global__ __launch_bounds__(256) void gemm_mfma_kernel(const unsigned short* __restrict__ hb,
                                                        const unsigned short* __restrict__ Wt,
                                                        const float* __restrict__ dinv,
                                                        unsigned int* __restrict__ outu) {
    __shared__ float ls[64 * LSTRIDE];  // ~33 KB
    const int wave = threadIdx.x >> 6, lane = threadIdx.x & 63;
    const int m15 = lane & 15, quad = lane >> 4;
    const int row0 = blockIdx.x * 64;
    const int arow = row0 + wave * 16 + m15;

    bf16x8 a[K / 32];
#pragma unroll
    for (int ks = 0; ks < K / 32; ks++)
        a[ks] = *(const bf16x8*)&hb[(size_t)ks * (NPAD * 32) + arow * 32 + quad * 8];

    const int lrow = wave * 16 + quad * 4;
    float dv[4];
#pragma unroll
    for (int r = 0; r < 4; r++) dv[r] = dinv[row0 + lrow + r];

#pragma unroll
    for (int ct = 0; ct < 8; ct++) {
        f32x4 acc = {0.f, 0.f, 0.f, 0.f};
#pragma unroll
        for (int ks = 0; ks < K / 32; ks++) {
            bf16x8 b = *(const bf16x8*)&Wt[(ct * 16 + m15) * K + ks * 32 + quad * 8];
            acc = __builtin_amdgcn_mfma_f32_16x16x32_bf16(a[ks], b, acc, 0, 0, 0);
        }
#pragma unroll
        for (int r = 0; r < 4; r++)
            ls[(lrow + r) * LSTRIDE + ct * 16 + m15] = acc[r] * dv[r];
    }
    __syncthreads();

    // packed coalesced stores: 1024 uint4 per block, 4 per thread
#pragma unroll
    for (int k = 0; k < 4; k++) {
        int idx = threadIdx.x + 256 * k;
        int c = idx >> 8, row = (idx >> 2) & 63, q = idx & 3;
        const float* p = &ls[row * LSTRIDE + c * 32 + q * 8];
        uint4 o;
        o.x = pack_bf16x2(p[0], p[1]);
        o.y = pack_bf16x2(p[2], p[3]);
        o.z = pack_bf16x2(p[4], p[5]);
        o.w = pack_bf16x2(p[6], p[7]);
        *(uint4*)&outu[(size_t)c * (NPAD * CHUNK_U) + (size_t)(row0 + row) * CHUNK_U + q * 4] = o;
    }
}

// ============ feature-chunked gather aggregation, node-per-group ============
// CSR rows padded to x8 with DUMMY (zero row) -> tail-free, aligned int4 loads.
template <bool RELU_BIAS>
__global__ __launch_bounds__(256) void agg_kernel(const unsigned int* __restrict__ hwc,
                                                  const int* __restrict__ rowptr,
                                                  const int* __restrict__ csr,
                                                  const float* __restrict__ dinv,
                                                  const float* __restrict__ bias,
                                                  unsigned int* __restrict__ outc) {
    const int chunk = blockIdx.x / (NN / 16);
    const int nb = blockIdx.x % (NN / 16);
    const int wave = threadIdx.x >> 6, lane = threadIdx.x & 63;
    const int g = lane >> 4, u = lane & 15;
    const int n = nb * 16 + wave * 4 + g;
    const unsigned int* __restrict__ slice = hwc + (size_t)chunk * (NPAD * CHUNK_U);

    unsigned int sv = slice[n * CHUNK_U + u];  // self-loop term
    float ax = bf_lo(sv), ay = bf_hi(sv);

    const int beg = rowptr[n], end = rowptr[n + 1];  // both multiples of 8
    for (int i = beg; i < end; i += 8) {
        int4 ca = *(const int4*)&csr[i];
        int4 cb = *(const int4*)&csr[i + 4];
        unsigned int v0 = slice[ca.x * CHUNK_U + u], v1 = slice[ca.y * CHUNK_U + u];
        unsigned int v2 = slice[ca.z * CHUNK_U + u], v3 = slice[ca.w * CHUNK_U + u];
        unsigned int v4 = slice[cb.x * CHUNK_U + u], v5 = slice[cb.y * CHUNK_U + u];
        unsigned int v6 = slice[cb.z * CHUNK_U + u], v7 = slice[cb.w * CHUNK_U + u];
        ax += bf_lo(v0) + bf_lo(v1) + bf_lo(v2) + bf_lo(v3) +
              bf_lo(v4) + bf_lo(v5) + bf_lo(v6) + bf_lo(v7);
        ay += bf_hi(v0) + bf_hi(v1) + bf_hi(v2) + bf_hi(v3) +
              bf_hi(v4) + bf_hi(v5) + bf_hi(v6) + bf_hi(v7);
    }

    float d = dinv[n];
    ax *= d;
    ay *= d;
    if (RELU_BIAS) {
        float2 bv = ((const float2*)bias)[chunk * CHUNK_U + u];
        ax = fmaxf(ax + bv.x, 0.f);
        ay = fmaxf(ay + bv.y, 0.f);
    }
    outc[(size_t)chunk * (NPAD * CHUNK_U) + n * CHUNK_U + u] = pack_bf16x2(ax, ay);
}

// ======== pooling: block-local segment reduction (batch sorted), chunked bf16 in ========
__global__ __launch_bounds__(256) void pool_kernel(const unsigned int* __restrict__ hbu,
                                                   const float* __restrict__ b4,
                                                   const int* __restrict__ batch,
                                                   float* __restrict__ pooled,
                                                   float* __restrict__ cnt) {
    __shared__ int bs[POOL_NODES];
    const int tid = threadIdx.x;
    const int n0 = blockIdx.x * POOL_NODES;
    for (int i = tid; i < POOL_NODES; i += 256) bs[i] = batch[n0 + i];
    __syncthreads();
    const int c2 = tid & 63;                 // feature-uint index 0..63
    const int chunk = c2 >> 4, u = c2 & 15;
    const int rsub = tid >> 6;  // 0..3
    float2 bb = ((const float2*)b4)[c2];
    float2 acc = {0.f, 0.f};
    float cacc = 0.f;
    int curg = bs[rsub];
    const size_t coff = (size_t)chunk * (NPAD * CHUNK_U) + u;
    for (int r = rsub; r < POOL_NODES; r += 4) {
        int g = bs[r];
        if (g != curg) {
            atomicAdd(&pooled[curg * H + c2 * 2], acc.x);
            atomicAdd(&pooled[curg * H + c2 * 2 + 1], acc.y);
            if (c2 == 0) atomicAdd(&cnt[curg], cacc);
            acc.x = acc.y = 0.f;
            cacc = 0.f;
            curg = g;
        }
        unsigned int v = hbu[coff + (size_t)(n0 + r) * CHUNK_U];
        acc.x += bf_lo(v) + bb.x;
        acc.y += bf_hi(v) + bb.y;
        cacc += 1.f;
    }
    atomicAdd(&pooled[curg * H + c2 * 2], acc.x);
    atomicAdd(&pooled[curg * H + c2 * 2 + 1], acc.y);
    if (c2 == 0) atomicAdd(&cnt[curg], cacc);
}

// ================= final MLP (single block) =================
__global__ __launch_bounds__(1024) void mlp_kernel(const float* __restrict__ pooled,
                                                   const float* __restrict__ cnt,
                                                   const float* __restrict__ lw1,
                                                   const float* __restrict__ lb1,
                                                   const float* __restrict__ lw2,
                                                   const float* __restrict__ lb2,
                                                   float* __restrict__ out) {
    __shared__ float mean_s[NG * H];
    __shared__ float hid_s[NG * 64];
    int tid = threadIdx.x;
    for (int i = tid; i < NG * H; i += 1024) {
        int g = i >> 7;
        mean_s[i] = pooled[i] / fmaxf(cnt[g], 1.0f);
    }
    __syncthreads();
    {
        int g = tid >> 6, j = tid & 63;
        float acc = lb1[j];
        for (int f = 0; f < H; f++) acc += mean_s[g * H + f] * lw1[f * 64 + j];
        hid_s[g * 64 + j] = fmaxf(acc, 0.f);
    }
    __syncthreads();
    if (tid < 32) {
        int g = tid >> 1, c = tid & 1;
        float acc = lb2[c];
        for (int j = 0; j < 64; j++) acc += hid_s[g * 64 + j] * lw2[j * 2 + c];
        out[g * 2 + c] = acc;
    }
}

extern "C" void kernel_launch(void* const* d_in, const int* in_sizes, int n_in,
                              void* d_out, int out_size, void* d_ws, size_t ws_size,
                              hipStream_t stream) {
    const float* x = (const float*)d_in[0];
    const int* ei = (const int*)d_in[1];
    const int* batch = (const int*)d_in[2];
    const float* W1 = (const float*)d_in[3];
    const float* b1 = (const float*)d_in[4];
    const float* W2 = (const float*)d_in[5];
    const float* b2 = (const float*)d_in[6];
    const float* W3 = (const float*)d_in[7];
    const float* b3 = (const float*)d_in[8];
    const float* W4 = (const float*)d_in[9];
    const float* b4 = (const float*)d_in[10];
    const float* lw1 = (const float*)d_in[11];
    const float* lb1 = (const float*)d_in[12];
    const float* lw2 = (const float*)d_in[13];
    const float* lb2 = (const float*)d_in[14];
    float* out = (float*)d_out;

    // workspace layout (4-byte units); total ~41 MB
    int* wsi = (int*)d_ws;
    int* cnt = wsi;                                        // 50048
    int* bsumR = wsi + 50048;                              // 256
    int* bsumP = wsi + 50304;                              // 256
    int* rowptr = wsi + 50560;                             // 50064
    int* cursor = wsi + 100624;                            // 50048
    int* csr = wsi + 150672;                               // CSR_CAP
    float* dinv = (float*)(wsi + 1350672);                 // 50048
    unsigned short* Wt1 = (unsigned short*)(wsi + 1400720);  // 128*64
    unsigned short* Wt2 = (unsigned short*)(wsi + 1404816);  // 128*128
    unsigned short* Wt3 = (unsigned short*)(wsi + 1413008);
    unsigned short* Wt4 = (unsigned short*)(wsi + 1421200);
    unsigned short* xb = (unsigned short*)(wsi + 1429392);   // NPAD*64 (chunked)
    unsigned int* hb = (unsigned int*)(wsi + 3030928);       // NPAD*64 (chunked bf16x2)
    unsigned int* hwb = (unsigned int*)(wsi + 6234000);      // NPAD*64 (chunked bf16x2)
    float* pooled = (float*)(wsi + 9437072);                 // NG*H + NG
    float* pcnt = pooled + NG * H;
    int* gbase = wsi + 9439200;                              // 128
    unsigned int* ebuf = (unsigned int*)(wsi + 9439328);     // NE

    const int edgeBlocks = (NE + 255) / 256;   // 3125
    const int gemmBlocks = NPAD / 64;          // 782
    const int aggBlocks = 4 * (NN / 16);       // 12500, chunk-major

    // ---- CSR build (once; reused by all 4 layers) ----
    hipMemsetAsync(cnt, 0, NN * sizeof(int), stream);
    hist_kernel<<<edgeBlocks, 256, 0, stream>>>(ei + NE, cnt);
    scanA_kernel<<<SCAN_BLOCKS, 256, 0, stream>>>(cnt, bsumR, bsumP);
    scanB_kernel<<<1, 256, 0, stream>>>(bsumR, bsumP);
    scanC_kernel<<<SCAN_BLOCKS, 256, 0, stream>>>(cnt, bsumR, bsumP, rowptr, cursor, dinv, gbase);
    csr_init_kernel<<<(CSR_CAP + 255) / 256, 256, 0, stream>>>(csr);
    fillA_kernel<<<FILLA_BLOCKS, 256, 0, stream>>>(ei, gbase, ebuf);
    fillB_kernel<<<NBUCK, 256, 0, stream>>>(ebuf, gbase, cursor, csr);

    // ---- converts ----
    cvt_x_kernel<<<(NPAD * FIN) / 256, 256, 0, stream>>>(x, xb);
    cvt_w_all_kernel<<<(H * FIN + 3 * H * H) / 256, 256, 0, stream>>>(
        W1, W2, W3, W4, Wt1, Wt2, Wt3, Wt4);
    pad_zero_kernel<<<12, 256, 0, stream>>>(hb);

    // ---- layer 1 ----
    gemm_mfma_kernel<FIN><<<gemmBlocks, 256, 0, stream>>>(xb, Wt1, dinv, hwb);
    agg_kernel<true><<<aggBlocks, 256, 0, stream>>>(hwb, rowptr, csr, dinv, b1, hb);
    // ---- layer 2 ----
    gemm_mfma_kernel<H><<<gemmBlocks, 256, 0, stream>>>((unsigned short*)hb, Wt2, dinv, hwb);
    agg_kernel<true><<<aggBlocks, 256, 0, stream>>>(hwb, rowptr, csr, dinv, b2, hb);
    // ---- layer 3 ----
    gemm_mfma_kernel<H><<<gemmBlocks, 256, 0, stream>>>((unsigned short*)hb, Wt3, dinv, hwb);
    agg_kernel<true><<<aggBlocks, 256, 0, stream>>>(hwb, rowptr, csr, dinv, b3, hb);
    // ---- layer 4 (no relu/bias; b4 fused in pool) ----
    gemm_mfma_kernel<H><<<gemmBlocks, 256, 0, stream>>>((unsigned short*)hb, Wt4, dinv, hwb);
    agg_kernel<false><<<aggBlocks, 256, 0, stream>>>(hwb, rowptr, csr, dinv, nullptr, hb);

    // ---- pooling (fused +b4) + MLP ----
    hipMemsetAsync(pooled, 0, (NG * H + NG) * sizeof(float), stream);
    pool_kernel<<<POOL_BLOCKS, 256, 0, stream>>>(hb, b4, batch, pooled, pcnt);
    mlp_kernel<<<1, 1024, 0, stream>>>(pooled, pcnt, lw1, lb1, lw2, lb2, out);
}